// Round 6
// baseline (1118.803 us; speedup 1.0000x reference)
//
#include <hip/hip_runtime.h>
#include <math.h>

#define N_PTS 8192
#define M_PTS 2048
#define NM_PTS 10240
#define D_DIM 768
#define EPS_F 0.0025f
#define INV_EPS_F 400.0f
#define SINK_ITERS 50
#define QSCALE_F 12800.0f     // u16 units: (C/eps)*32  (step 1/32 nat)
#define R8_STEP_F 0.375f      // u8 residual step in nats = 12 u16 units
#define U16_TO_NAT 0.03125f
#define FREEZE_TOL 4.0e-3f    // nats; monotone-change bound -> |dS| <= ~5e-4

typedef __attribute__((ext_vector_type(8))) short short8;
typedef __attribute__((ext_vector_type(4))) float f32x4;

// Q8 / QT8 rows stored PERMUTED per 2048-col segment (r5-validated):
// byte position p = 32L + 4t + e holds logical column c = 256t + 4L + e,
// so lane L reads bytes [32L..32L+32) and bias floats hb4[64t + lane].

// ---------------------------------------------------------------------------
__device__ __forceinline__ unsigned short sk_f2bf(float f)
{
    const unsigned u = __float_as_uint(f);
    return (unsigned short)((u + 0x7fffu + ((u >> 16) & 1u)) >> 16);
}

__device__ __forceinline__ void sk_merge(float& m, float& s, float mc, float sc)
{
    const float nm = fmaxf(m, mc);
    s = s * __expf(m - nm) + sc * __expf(mc - nm);
    m = nm;
}

__device__ __forceinline__ void sk_z4(unsigned int w, const float* hbr, int o, float* z)
{
    z[o + 0] = fmaf((float)(w & 0xffu),         -R8_STEP_F, hbr[o + 0]);
    z[o + 1] = fmaf((float)((w >> 8) & 0xffu),  -R8_STEP_F, hbr[o + 1]);
    z[o + 2] = fmaf((float)((w >> 16) & 0xffu), -R8_STEP_F, hbr[o + 2]);
    z[o + 3] = fmaf((float)(w >> 24),           -R8_STEP_F, hbr[o + 3]);
}

__device__ __forceinline__ void sk_lse32(
    const uint4 q0, const uint4 q1, const float* hbr, float& mc, float& sc)
{
    float z[32];
    sk_z4(q0.x, hbr, 0, z);  sk_z4(q0.y, hbr, 4, z);
    sk_z4(q0.z, hbr, 8, z);  sk_z4(q0.w, hbr, 12, z);
    sk_z4(q1.x, hbr, 16, z); sk_z4(q1.y, hbr, 20, z);
    sk_z4(q1.z, hbr, 24, z); sk_z4(q1.w, hbr, 28, z);
    mc = z[0];
    #pragma unroll
    for (int k = 1; k < 32; ++k) mc = fmaxf(mc, z[k]);
    sc = 0.f;
    #pragma unroll
    for (int k = 0; k < 32; ++k) sc += __expf(z[k] - mc);
}

// ---------------------------------------------------------------------------
// init: LW = (log h | log hi), hbF = log hi (g=0), R32 = INT_MAX, ctrl = 0
// ctrl layout: [k*32] k<64 = frozen-flag replicas; [2048+it] = max|dF| bits
// ---------------------------------------------------------------------------
__global__ __launch_bounds__(256) void sk_init(
    const float* __restrict__ h, const float* __restrict__ hi,
    float* __restrict__ lw, float* __restrict__ hbF, int* __restrict__ r32,
    int* __restrict__ ctrl)
{
    const int t = blockIdx.x * 256 + threadIdx.x;
    if (t < N_PTS) { lw[t] = logf(h[t]); r32[t] = 0x7fffffff; }
    else if (t < NM_PTS) {
        const float v = logf(hi[t - N_PTS]);
        lw[t] = v; hbF[t - N_PTS] = v;
    }
    if (t < 4096) ctrl[t] = 0;
}

// ---------------------------------------------------------------------------
__global__ __launch_bounds__(256) void sk_cast(
    const float* __restrict__ src, unsigned short* __restrict__ dst)
{
    const int t = blockIdx.x * 256 + threadIdx.x;
    const float4 v = ((const float4*)src)[t];
    ushort4 o;
    o.x = sk_f2bf(v.x); o.y = sk_f2bf(v.y); o.z = sk_f2bf(v.z); o.w = sk_f2bf(v.w);
    ((ushort4*)dst)[t] = o;
}

// ---------------------------------------------------------------------------
// MFMA bf16 NT-GEMM, 128x128 tile, 256 thr.
// MODE 0: Xb = bf16(dot) via LDS-transpose epilogue (r4-validated).
// MODE 1: q = sat_u16(relu(xs+ys-dot)*12800) -> LDS tile [gn][gm] (stride
//         136) -> coalesced 16B QTu16 row writes; per-row atomicMin -> R32.
// ---------------------------------------------------------------------------
template<int MODE>
__global__ __launch_bounds__(256) void sk_mfma(
    const unsigned short* __restrict__ A, const unsigned short* __restrict__ B,
    unsigned short* __restrict__ Xb,
    unsigned short* __restrict__ QT, int* __restrict__ R32,
    const float* __restrict__ xs, const float* __restrict__ ys)
{
    constexpr int LS = 40;
    __shared__ unsigned short Sh[MODE ? 17408 : 10240];  // MODE1: 128x136 tile
    __shared__ int rmin[128];
    unsigned short* As = Sh;
    unsigned short* Bs = Sh + 5120;
    const int tid  = threadIdx.x;
    const int wave = tid >> 6, lane = tid & 63;
    const int quad = lane >> 4, l16 = lane & 15;
    const int row0 = blockIdx.y * 128, col0 = blockIdx.x * 128;
    const int wr = (wave >> 1) * 64, wc = (wave & 1) * 64;
    if (MODE == 1 && tid < 128) rmin[tid] = 0x7fffffff;

    const int sr = tid >> 2;
    const int sk = (tid & 3) * 8;
    const unsigned short* Ap  = A + (size_t)(row0 + sr) * D_DIM + sk;
    const unsigned short* Ap2 = Ap + (size_t)64 * D_DIM;
    const unsigned short* Bp  = B + (size_t)(col0 + sr) * D_DIM + sk;
    const unsigned short* Bp2 = Bp + (size_t)64 * D_DIM;

    f32x4 acc[4][4] = {};

    for (int k0 = 0; k0 < D_DIM; k0 += 32) {
        const short8 a0 = *(const short8*)(Ap + k0);
        const short8 a1 = *(const short8*)(Ap2 + k0);
        const short8 b0 = *(const short8*)(Bp + k0);
        const short8 b1 = *(const short8*)(Bp2 + k0);
        __syncthreads();
        *(short8*)(As + sr * LS + sk)        = a0;
        *(short8*)(As + (sr + 64) * LS + sk) = a1;
        *(short8*)(Bs + sr * LS + sk)        = b0;
        *(short8*)(Bs + (sr + 64) * LS + sk) = b1;
        __syncthreads();
        short8 af[4], bfr[4];
        #pragma unroll
        for (int i = 0; i < 4; ++i) {
            af[i]  = *(const short8*)(As + (wr + i * 16 + l16) * LS + quad * 8);
            bfr[i] = *(const short8*)(Bs + (wc + i * 16 + l16) * LS + quad * 8);
        }
        #pragma unroll
        for (int i = 0; i < 4; ++i)
            #pragma unroll
            for (int j = 0; j < 4; ++j)
                acc[i][j] = __builtin_amdgcn_mfma_f32_16x16x32_bf16(
                    af[i], bfr[j], acc[i][j], 0, 0, 0);
    }

    if (MODE == 0) {
        unsigned short* sl = As;
        const int sgrp = wr >> 6;
        const int osg = tid >> 7, orow = (tid >> 3) & 15, oc16 = (tid & 7) * 16;
        #pragma unroll
        for (int i = 0; i < 4; ++i) {
            __syncthreads();
            #pragma unroll
            for (int j = 0; j < 4; ++j)
                #pragma unroll
                for (int r = 0; r < 4; ++r)
                    sl[sgrp * 2176 + (quad * 4 + r) * 136 + wc + j * 16 + l16] =
                        sk_f2bf(acc[i][j][r]);
            __syncthreads();
            const unsigned short* src = sl + osg * 2176 + orow * 136 + oc16;
            const short8 v0 = *(const short8*)src;
            const short8 v1 = *(const short8*)(src + 8);
            unsigned short* dst = Xb +
                (size_t)(row0 + osg * 64 + i * 16 + orow) * D_DIM + col0 + oc16;
            *(short8*)dst = v0;
            *(short8*)(dst + 8) = v1;
        }
    } else {
        unsigned short* tile = Sh;          // 128 x 136, [gn][gm]
        __syncthreads();                    // done reading As/Bs
        const int gm0l = wr + quad * 4;
        const int gn0l = wc + l16;
        #pragma unroll
        for (int i = 0; i < 4; ++i) {
            float xv[4];
            #pragma unroll
            for (int r = 0; r < 4; ++r) xv[r] = xs[row0 + gm0l + i * 16 + r];
            int qmn[4] = {0x7fffffff, 0x7fffffff, 0x7fffffff, 0x7fffffff};
            #pragma unroll
            for (int j = 0; j < 4; ++j) {
                const int gn = gn0l + j * 16;
                const float ysv = ys[col0 + gn];
                unsigned short q4[4];
                #pragma unroll
                for (int r = 0; r < 4; ++r) {
                    const float c = fmaxf(xv[r] + ysv - acc[i][j][r], 0.f);
                    const int iq = (int)fminf(fmaf(c, QSCALE_F, 0.5f), 65535.f);
                    qmn[r] = min(qmn[r], iq);
                    q4[r] = (unsigned short)iq;
                }
                *(ushort4*)&tile[gn * 136 + gm0l + i * 16] = *(const ushort4*)q4;
            }
            #pragma unroll
            for (int r = 0; r < 4; ++r)
                atomicMin(&rmin[gm0l + i * 16 + r], qmn[r]);
        }
        __syncthreads();
        const int gn = tid >> 1, gmh = (tid & 1) * 64;
        const unsigned short* srcp = tile + gn * 136 + gmh;
        unsigned short* dstp = QT + (size_t)(col0 + gn) * N_PTS + row0 + gmh;
        #pragma unroll
        for (int k = 0; k < 8; ++k)
            *(short8*)(dstp + k * 8) = *(const short8*)(srcp + k * 8);
        if (tid < 128) atomicMin(&R32[row0 + tid], rmin[tid]);
    }
}

// ---------------------------------------------------------------------------
__global__ __launch_bounds__(256) void sk_row_norms(
    const unsigned short* __restrict__ Xb, float* __restrict__ XS)
{
    const int row  = blockIdx.x * 4 + (threadIdx.x >> 6);
    const int lane = threadIdx.x & 63;
    const unsigned int* p = (const unsigned int*)(Xb + (size_t)row * D_DIM);
    float s = 0.f;
    #pragma unroll
    for (int k = 0; k < 6; ++k) {
        const unsigned int u = p[lane + k * 64];
        const float f0 = __uint_as_float(u << 16);
        const float f1 = __uint_as_float(u & 0xffff0000u);
        s = fmaf(f0, f0, s); s = fmaf(f1, f1, s);
    }
    #pragma unroll
    for (int off = 32; off; off >>= 1) s += __shfl_xor(s, off, 64);
    if (lane == 0) XS[row] = 0.5f * s;
}

// ---------------------------------------------------------------------------
// QTu16 -> Q8 (transpose + permute + u8 requant vs R32[i])  (r5-validated)
// ---------------------------------------------------------------------------
__global__ __launch_bounds__(256) void sk_transq(
    const unsigned short* __restrict__ QT, const int* __restrict__ R32,
    unsigned char* __restrict__ Q8)
{
    __shared__ unsigned short tile[64][72];
    const int tid = threadIdx.x;
    const int J0 = blockIdx.x * 64;
    const int I0 = blockIdx.y * 64;
    {
        const int tj = tid >> 2, ti = (tid & 3) * 16;
        const uint4* src = (const uint4*)(QT + (size_t)(J0 + tj) * N_PTS + I0 + ti);
        const uint4 a = src[0], b = src[1];
        *(uint4*)&tile[tj][ti] = a;
        *(uint4*)&tile[tj][ti + 8] = b;
    }
    __syncthreads();
    const int li = tid >> 2, lj = (tid & 3) * 16;
    const int R = R32[I0 + li];
    const int L0 = (J0 >> 2) & 63;
    const int t0 = J0 >> 8;
    unsigned char* orow = Q8 + (size_t)(I0 + li) * M_PTS;
    #pragma unroll
    for (int q = 0; q < 4; ++q) {
        unsigned char ob[4];
        #pragma unroll
        for (int e = 0; e < 4; ++e) {
            const int qv = (int)tile[lj + q * 4 + e][li];
            ob[e] = (unsigned char)fminf(fmaf((float)(qv - R), 1.0f / 12.0f, 0.5f), 255.f);
        }
        *(unsigned int*)(orow + 32 * (L0 + (lj >> 2) + q) + 4 * t0) =
            *(const unsigned int*)ob;
    }
}

// ---------------------------------------------------------------------------
// QTu16 -> QT8 (permuted per segment, u8 requant vs R32[i]) (r5-validated)
// ---------------------------------------------------------------------------
__global__ __launch_bounds__(256) void sk_requant_qt(
    const unsigned short* __restrict__ QT, const int* __restrict__ R32,
    unsigned char* __restrict__ QT8)
{
    const size_t base = ((size_t)blockIdx.x * 256 + threadIdx.x) * 16;
    const int i0 = (int)(base & (size_t)(N_PTS - 1));
    const size_t rowb = base & ~(size_t)(N_PTS - 1);
    const uint4* src = (const uint4*)(QT + base);
    const uint4 a = src[0], b = src[1];
    unsigned int qs[8] = {a.x, a.y, a.z, a.w, b.x, b.y, b.z, b.w};
    const int* rp = R32 + i0;
    const int s  = i0 >> 11;
    const int ip = i0 & 2047;
    const int t  = ip >> 8;
    const int L0 = (ip >> 2) & 63;
    unsigned char* orow = QT8 + rowb + 2048 * s + 4 * t;
    #pragma unroll
    for (int q = 0; q < 4; ++q) {
        unsigned char ob[4];
        #pragma unroll
        for (int e = 0; e < 4; ++e) {
            const int k = q * 4 + e;
            const int qv = (int)((qs[k >> 1] >> ((k & 1) * 16)) & 0xffffu);
            ob[e] = (unsigned char)fminf(fmaf((float)(qv - rp[k]), 1.0f / 12.0f, 0.5f), 255.f);
        }
        *(unsigned int*)(orow + 32 * (L0 + q)) = *(const unsigned int*)ob;
    }
}

// ---------------------------------------------------------------------------
// F softmin: 2 rows/wave, 512 blocks x 512 thr. hb loaded once per wave.
// Tracks max|delta hbG| -> ctrl[2048+it] for the convergence freeze.
// ---------------------------------------------------------------------------
template<bool FINAL>
__global__ __launch_bounds__(512, 4) void sk_smF(
    const unsigned char* __restrict__ Q8, const float* __restrict__ hbF,
    const float* __restrict__ LW, const int* __restrict__ R32,
    float* __restrict__ outv, int* __restrict__ ctrl, const int it)
{
    __shared__ float dred[8];
    __shared__ int sflag;
    const int tid = threadIdx.x, wave = tid >> 6, lane = tid & 63;
    if (!FINAL) {
        if (tid == 0) sflag = atomicOr(&ctrl[(blockIdx.x & 63) << 5], 0);
        __syncthreads();
        if (sflag) return;
    }
    const int row0 = (blockIdx.x * 8 + wave) * 2;
    const uint4* qp0 = (const uint4*)(Q8 + (size_t)row0 * M_PTS);
    const uint4* qp1 = (const uint4*)(Q8 + (size_t)(row0 + 1) * M_PTS);
    const uint4 a0 = qp0[lane * 2], a1 = qp0[lane * 2 + 1];
    const uint4 b0 = qp1[lane * 2], b1 = qp1[lane * 2 + 1];
    float hbr[32];
    const float4* hb4 = (const float4*)hbF;
    #pragma unroll
    for (int t = 0; t < 8; ++t) {
        const float4 v = hb4[t * 64 + lane];
        hbr[t * 4 + 0] = v.x; hbr[t * 4 + 1] = v.y;
        hbr[t * 4 + 2] = v.z; hbr[t * 4 + 3] = v.w;
    }
    float m0, s0, m1, s1;
    sk_lse32(a0, a1, hbr, m0, s0);
    sk_lse32(b0, b1, hbr, m1, s1);
    #pragma unroll
    for (int off = 1; off < 64; off <<= 1) {
        float mm = __shfl_xor(m0, off, 64), ss = __shfl_xor(s0, off, 64);
        sk_merge(m0, s0, mm, ss);
        mm = __shfl_xor(m1, off, 64); ss = __shfl_xor(s1, off, 64);
        sk_merge(m1, s1, mm, ss);
    }
    float dmax = 0.f;
    if (lane == 0) {
        const float lse0 = m0 + __logf(s0);
        const float lse1 = m1 + __logf(s1);
        if (FINAL) {
            outv[row0]     = EPS_F * ((float)R32[row0] * U16_TO_NAT - lse0);
            outv[row0 + 1] = EPS_F * ((float)R32[row0 + 1] * U16_TO_NAT - lse1);
        } else {
            const float nv0 = LW[row0] - lse0;
            const float nv1 = LW[row0 + 1] - lse1;
            dmax = fmaxf(fabsf(nv0 - outv[row0]), fabsf(nv1 - outv[row0 + 1]));
            outv[row0] = nv0; outv[row0 + 1] = nv1;
        }
    }
    if (!FINAL) {
        if (lane == 0) dred[wave] = dmax;
        __syncthreads();
        if (tid == 0) {
            float d = dred[0];
            #pragma unroll
            for (int k = 1; k < 8; ++k) d = fmaxf(d, dred[k]);
            atomicMax(&ctrl[2048 + it], __float_as_int(d));
        }
    }
}

// ---------------------------------------------------------------------------
// G softmin: 2 rows x 1 segment per wave, 512 blocks x 512 thr (4 rows/blk,
// 4 segs via waves), LDS merge. Block 0 decides the freeze from F's delta.
// ---------------------------------------------------------------------------
__global__ __launch_bounds__(512, 4) void sk_smG(
    const unsigned char* __restrict__ QT8, const float* __restrict__ hbG,
    const float* __restrict__ LW, float* __restrict__ hbF,
    int* __restrict__ ctrl, const int it)
{
    __shared__ float mred[2][4][2], sred[2][4][2];
    __shared__ int sflag;
    const int tid = threadIdx.x, wave = tid >> 6, lane = tid & 63;
    if (tid == 0) {
        const int fl = atomicOr(&ctrl[(blockIdx.x & 63) << 5], 0);
        if (!fl && blockIdx.x == 0) {
            const int d = atomicOr(&ctrl[2048 + it], 0);
            if (__int_as_float(d) < FREEZE_TOL)
                for (int k = 0; k < 64; ++k) atomicOr(&ctrl[k << 5], 1);
        }
        sflag = fl;
    }
    __syncthreads();
    if (sflag) return;

    const int p   = wave >> 2;      // row pair in block
    const int seg = wave & 3;       // 2048-col segment
    const int row0 = blockIdx.x * 4 + p * 2;
    float hbr[32];
    const float4* hb4 = (const float4*)hbG;
    #pragma unroll
    for (int t = 0; t < 8; ++t) {
        const float4 v = hb4[seg * 512 + t * 64 + lane];
        hbr[t * 4 + 0] = v.x; hbr[t * 4 + 1] = v.y;
        hbr[t * 4 + 2] = v.z; hbr[t * 4 + 3] = v.w;
    }
    const uint4* qp0 = (const uint4*)(QT8 + (size_t)row0 * N_PTS);
    const uint4* qp1 = (const uint4*)(QT8 + (size_t)(row0 + 1) * N_PTS);
    const uint4 a0 = qp0[seg * 128 + lane * 2], a1 = qp0[seg * 128 + lane * 2 + 1];
    const uint4 b0 = qp1[seg * 128 + lane * 2], b1 = qp1[seg * 128 + lane * 2 + 1];
    float m0, s0, m1, s1;
    sk_lse32(a0, a1, hbr, m0, s0);
    sk_lse32(b0, b1, hbr, m1, s1);
    #pragma unroll
    for (int off = 1; off < 64; off <<= 1) {
        float mm = __shfl_xor(m0, off, 64), ss = __shfl_xor(s0, off, 64);
        sk_merge(m0, s0, mm, ss);
        mm = __shfl_xor(m1, off, 64); ss = __shfl_xor(s1, off, 64);
        sk_merge(m1, s1, mm, ss);
    }
    if (lane == 0) {
        mred[p][seg][0] = m0; sred[p][seg][0] = s0;
        mred[p][seg][1] = m1; sred[p][seg][1] = s1;
    }
    __syncthreads();
    if (seg == 0 && lane < 2) {
        float m = mred[p][0][lane], s = sred[p][0][lane];
        #pragma unroll
        for (int g = 1; g < 4; ++g) sk_merge(m, s, mred[p][g][lane], sred[p][g][lane]);
        const int row = row0 + lane;
        hbF[row] = LW[N_PTS + row] - (m + __logf(s));
    }
}

// ---------------------------------------------------------------------------
__global__ __launch_bounds__(1024) void sk_finalize(
    const float* __restrict__ fo, const float* __restrict__ hbF,
    const float* __restrict__ h, const float* __restrict__ hi,
    const float* __restrict__ lw, float* __restrict__ out)
{
    const int tid = threadIdx.x;
    float acc = 0.f;
    for (int r = tid; r < N_PTS; r += 1024)
        acc += h[r] * (fo[r] + 0.5f * EPS_F * lw[r]);
    for (int j = tid; j < M_PTS; j += 1024)
        acc += hi[j] * EPS_F * (hbF[j] - 0.5f * lw[N_PTS + j]);
    __shared__ float red[1024];
    red[tid] = acc;
    __syncthreads();
    for (int st = 512; st; st >>= 1) {
        if (tid < st) red[tid] += red[tid + st];
        __syncthreads();
    }
    if (tid == 0) out[0] = expf(-red[0]);
}

// ---------------------------------------------------------------------------
extern "C" void kernel_launch(void* const* d_in, const int* in_sizes, int n_in,
                              void* d_out, int out_size, void* d_ws, size_t ws_size,
                              hipStream_t stream)
{
    const float* dpts = (const float*)d_in[0];
    const float* spts = (const float*)d_in[1];
    const float* h    = (const float*)d_in[2];
    const float* hiw  = (const float*)d_in[3];
    const float* W    = (const float*)d_in[4];
    float* out = (float*)d_out;

    float* XS  = (float*)d_ws;                        // NM
    float* LW  = XS + NM_PTS;                         // NM (la | lb)
    float* HBF = LW + NM_PTS;                         // M
    float* HBG = HBF + M_PTS;                         // N
    float* FO  = HBG + N_PTS;                         // N
    int*   R32 = (int*)(FO + N_PTS);                  // N
    int*   CT  = R32 + N_PTS;                         // 4096 control
    unsigned short* Db = (unsigned short*)(CT + 4096);          // NM x D bf16
    unsigned short* Wb = Db + (size_t)NM_PTS * D_DIM;           // D x D bf16
    unsigned short* Xb = Wb + (size_t)D_DIM * D_DIM;            // NM x D bf16
    unsigned short* QTu = Xb + (size_t)NM_PTS * D_DIM;          // M x N u16
    unsigned char*  Q8  = (unsigned char*)(QTu + (size_t)M_PTS * N_PTS); // N x M u8
    unsigned char*  QT8 = Q8 + (size_t)N_PTS * M_PTS;           // M x N u8

    sk_init<<<NM_PTS / 256, 256, 0, stream>>>(h, hiw, LW, HBF, R32, CT);

    sk_cast<<<(size_t)N_PTS * D_DIM / 1024, 256, 0, stream>>>(dpts, Db);
    sk_cast<<<(size_t)M_PTS * D_DIM / 1024, 256, 0, stream>>>(
        spts, Db + (size_t)N_PTS * D_DIM);
    sk_cast<<<(size_t)D_DIM * D_DIM / 1024, 256, 0, stream>>>(W, Wb);

    sk_mfma<0><<<dim3(D_DIM / 128, NM_PTS / 128), 256, 0, stream>>>(
        Db, Wb, Xb, nullptr, nullptr, nullptr, nullptr);

    sk_row_norms<<<NM_PTS / 4, 256, 0, stream>>>(Xb, XS);

    sk_mfma<1><<<dim3(M_PTS / 128, N_PTS / 128), 256, 0, stream>>>(
        Xb, Xb + (size_t)N_PTS * D_DIM, nullptr, QTu, R32, XS, XS + N_PTS);

    sk_transq<<<dim3(M_PTS / 64, N_PTS / 64), 256, 0, stream>>>(QTu, R32, Q8);
    sk_requant_qt<<<(size_t)M_PTS * N_PTS / 4096, 256, 0, stream>>>(QTu, R32, QT8);

    for (int it = 0; it < SINK_ITERS; ++it) {
        sk_smF<false><<<N_PTS / 16, 512, 0, stream>>>(Q8, HBF, LW, R32, HBG, CT, it);
        sk_smG       <<<M_PTS / 4,  512, 0, stream>>>(QT8, HBG, LW, HBF, CT, it);
    }
    sk_smF<true><<<N_PTS / 16, 512, 0, stream>>>(Q8, HBF, LW, R32, FO, CT, 0);

    sk_finalize<<<1, 1024, 0, stream>>>(FO, HBF, h, hiw, LW, out);
}